// Round 2
// baseline (9820.021 us; speedup 1.0000x reference)
//
#include <hip/hip_runtime.h>
#include <math.h>

#define V 32000
#define D 512
#define H 8
#define NL 4
#define HID 2048
#define NE 8
#define T 2048
#define HD 64

// ---------------------------------------------------------------- embedding
__global__ __launch_bounds__(256) void embed_kernel(const int* __restrict__ ids,
                                                    const float* __restrict__ emb,
                                                    float* __restrict__ x) {
  int idx = blockIdx.x * 256 + threadIdx.x;   // T*D total
  int t = idx >> 9;
  x[idx] = emb[(size_t)ids[t] * D + (idx & 511)];
}

// ---------------------------------------------------------------- rope cache (f64 once)
__global__ __launch_bounds__(256) void rope_cache_kernel(float* __restrict__ cost,
                                                         float* __restrict__ sint) {
  int idx = blockIdx.x * 256 + threadIdx.x;   // T*32 total
  int t = idx >> 5, j = idx & 31;
  double inv = pow(10000.0, -(double)j / 32.0);
  double ang = (double)t * inv;
  cost[idx] = (float)cos(ang);
  sint[idx] = (float)sin(ang);
}

// ---------------------------------------------------------------- rmsnorm (block per token)
__global__ __launch_bounds__(256) void rmsnorm_kernel(const float* __restrict__ in,
                                                      const float* __restrict__ w,
                                                      float* __restrict__ out) {
  int t = blockIdx.x;
  int tid = threadIdx.x;
  float a = in[t * D + tid];
  float b = in[t * D + tid + 256];
  float ss = a * a + b * b;
  #pragma unroll
  for (int off = 32; off; off >>= 1) ss += __shfl_down(ss, off);
  __shared__ float red[4];
  if ((tid & 63) == 0) red[tid >> 6] = ss;
  __syncthreads();
  float tot = red[0] + red[1] + red[2] + red[3];
  float inv = rsqrtf(tot * (1.0f / D) + 1e-6f);
  out[t * D + tid]       = a * inv * w[tid];
  out[t * D + tid + 256] = b * inv * w[tid + 256];
}

// ================================================================ 64x64 fp32 tile GEMM helpers
// Staging: A 64rows x 16k -> AsT[16][68] (transposed), B 16k x 64cols -> Bs[16][68]
// float4 global loads, vector LDS where possible. 256 threads.

// ---------------------------------------------------------------- fused QKV GEMM (N=1536)
__global__ __launch_bounds__(256) void gemm_qkv_kernel(const float* __restrict__ A,
    const float* __restrict__ wq, const float* __restrict__ wk, const float* __restrict__ wv,
    float* __restrict__ q, float* __restrict__ k, float* __restrict__ v) {
  __shared__ float AsT[16][68];
  __shared__ float Bs[16][68];
  int tid = threadIdx.x;
  int cg = blockIdx.x * 64;            // 0..1535
  int row0 = blockIdx.y * 64;
  int m = cg >> 9;                     // 0=q 1=k 2=v
  const float* W = (m == 0) ? wq : (m == 1) ? wk : wv;
  float* O = (m == 0) ? q : (m == 1) ? k : v;
  int col0 = cg & 511;
  int tx = tid & 15, ty = tid >> 4;
  int ar = tid >> 2, akq = (tid & 3) * 4;      // A staging coords
  int bk = tid >> 4, bcq = (tid & 15) * 4;     // B staging coords
  float acc[4][4] = {};
  for (int k0 = 0; k0 < D; k0 += 16) {
    float4 a4 = *(const float4*)&A[(row0 + ar) * D + k0 + akq];
    float4 b4 = *(const float4*)&W[(k0 + bk) * D + col0 + bcq];
    AsT[akq + 0][ar] = a4.x; AsT[akq + 1][ar] = a4.y;
    AsT[akq + 2][ar] = a4.z; AsT[akq + 3][ar] = a4.w;
    *(float4*)&Bs[bk][bcq] = b4;
    __syncthreads();
    #pragma unroll
    for (int kk = 0; kk < 16; kk++) {
      float4 av = *(const float4*)&AsT[kk][ty * 4];
      float4 bv = *(const float4*)&Bs[kk][tx * 4];
      float a[4] = {av.x, av.y, av.z, av.w};
      float b[4] = {bv.x, bv.y, bv.z, bv.w};
      #pragma unroll
      for (int i = 0; i < 4; i++)
        #pragma unroll
        for (int j = 0; j < 4; j++) acc[i][j] += a[i] * b[j];
    }
    __syncthreads();
  }
  #pragma unroll
  for (int i = 0; i < 4; i++) {
    int t = row0 + ty * 4 + i;
    #pragma unroll
    for (int j = 0; j < 4; j++) {
      int c = col0 + tx * 4 + j;
      int h = c >> 6, d = c & 63;
      O[((size_t)h * T + t) * HD + d] = acc[i][j];
    }
  }
}

// ---------------------------------------------------------------- WO GEMM + residual
__global__ __launch_bounds__(256) void gemm_wo_kernel(const float* __restrict__ A,
    const float* __restrict__ W, float* __restrict__ x) {
  __shared__ float AsT[16][68];
  __shared__ float Bs[16][68];
  int tid = threadIdx.x;
  int col0 = blockIdx.x * 64;
  int row0 = blockIdx.y * 64;
  int tx = tid & 15, ty = tid >> 4;
  int ar = tid >> 2, akq = (tid & 3) * 4;
  int bk = tid >> 4, bcq = (tid & 15) * 4;
  float acc[4][4] = {};
  for (int k0 = 0; k0 < D; k0 += 16) {
    float4 a4 = *(const float4*)&A[(row0 + ar) * D + k0 + akq];
    float4 b4 = *(const float4*)&W[(k0 + bk) * D + col0 + bcq];
    AsT[akq + 0][ar] = a4.x; AsT[akq + 1][ar] = a4.y;
    AsT[akq + 2][ar] = a4.z; AsT[akq + 3][ar] = a4.w;
    *(float4*)&Bs[bk][bcq] = b4;
    __syncthreads();
    #pragma unroll
    for (int kk = 0; kk < 16; kk++) {
      float4 av = *(const float4*)&AsT[kk][ty * 4];
      float4 bv = *(const float4*)&Bs[kk][tx * 4];
      float a[4] = {av.x, av.y, av.z, av.w};
      float b[4] = {bv.x, bv.y, bv.z, bv.w};
      #pragma unroll
      for (int i = 0; i < 4; i++)
        #pragma unroll
        for (int j = 0; j < 4; j++) acc[i][j] += a[i] * b[j];
    }
    __syncthreads();
  }
  #pragma unroll
  for (int i = 0; i < 4; i++) {
    int t = row0 + ty * 4 + i;
    #pragma unroll
    for (int j = 0; j < 4; j++) {
      int c = col0 + tx * 4 + j;
      x[t * D + c] = x[t * D + c] + acc[i][j];
    }
  }
}

// ---------------------------------------------------------------- rope apply (q and k)
__global__ __launch_bounds__(256) void rope_apply_kernel(float* __restrict__ q, float* __restrict__ k,
    const float* __restrict__ cost, const float* __restrict__ sint) {
  int idx = blockIdx.x * 256 + threadIdx.x;  // H*T*32
  int h = idx >> 16;
  int rem = idx & 65535;                     // t*32 + j
  int t = rem >> 5, j = rem & 31;
  float c = cost[rem], s = sint[rem];
  size_t base = ((size_t)h * T + t) * HD;
  float x1 = q[base + j], x2 = q[base + j + 32];
  q[base + j]      = x1 * c - x2 * s;
  q[base + j + 32] = x2 * c + x1 * s;
  x1 = k[base + j]; x2 = k[base + j + 32];
  k[base + j]      = x1 * c - x2 * s;
  k[base + j + 32] = x2 * c + x1 * s;
}

// ---------------------------------------------------------------- attention (block per (t,h))
__global__ __launch_bounds__(256) void attn_kernel(const float* __restrict__ q,
    const float* __restrict__ k, const float* __restrict__ v, float* __restrict__ o) {
  int t = blockIdx.x, h = blockIdx.y;
  int n = t + 1;
  int tid = threadIdx.x;
  __shared__ float sc[T];
  __shared__ float qs[HD];
  __shared__ float red[4];
  __shared__ float pv[4][HD];
  const float* kh = k + (size_t)h * T * HD;
  const float* vh = v + (size_t)h * T * HD;
  if (tid < HD) qs[tid] = q[((size_t)h * T + t) * HD + tid];
  __syncthreads();
  for (int s = tid; s < n; s += 256) {
    const float* kr = kh + s * HD;
    float acc = 0.0f;
    #pragma unroll
    for (int d = 0; d < HD; d++) acc += qs[d] * kr[d];
    sc[s] = acc * 0.125f;
  }
  __syncthreads();
  float m = -3.0e38f;
  for (int s = tid; s < n; s += 256) m = fmaxf(m, sc[s]);
  #pragma unroll
  for (int off = 32; off; off >>= 1) m = fmaxf(m, __shfl_down(m, off));
  if ((tid & 63) == 0) red[tid >> 6] = m;
  __syncthreads();
  m = fmaxf(fmaxf(red[0], red[1]), fmaxf(red[2], red[3]));
  __syncthreads();
  float sum = 0.0f;
  for (int s = tid; s < n; s += 256) { float e = __expf(sc[s] - m); sc[s] = e; sum += e; }
  #pragma unroll
  for (int off = 32; off; off >>= 1) sum += __shfl_down(sum, off);
  if ((tid & 63) == 0) red[tid >> 6] = sum;
  __syncthreads();
  sum = red[0] + red[1] + red[2] + red[3];
  float inv = 1.0f / sum;
  int d = tid & 63, part = tid >> 6;
  float acc = 0.0f;
  for (int s = part; s < n; s += 4) acc += sc[s] * vh[s * HD + d];
  pv[part][d] = acc;
  __syncthreads();
  if (tid < HD) {
    float r = (pv[0][tid] + pv[1][tid] + pv[2][tid] + pv[3][tid]) * inv;
    o[t * D + h * HD + tid] = r;
  }
}

// ---------------------------------------------------------------- router: logits, top2, lists
__global__ __launch_bounds__(256) void router_kernel(const float* __restrict__ xn,
    const float* __restrict__ rw, float* __restrict__ wts,
    int* __restrict__ counts, int* __restrict__ lists) {
  int tid = threadIdx.x;
  int wv_ = tid >> 6, lane = tid & 63;
  int t = blockIdx.x * 4 + wv_;
  float p[NE] = {};
  #pragma unroll
  for (int i = 0; i < D / 64; i++) {
    int d = lane + i * 64;
    float xd = xn[t * D + d];
    #pragma unroll
    for (int e = 0; e < NE; e++) p[e] += xd * rw[d * NE + e];
  }
  #pragma unroll
  for (int e = 0; e < NE; e++) {
    #pragma unroll
    for (int off = 32; off; off >>= 1) p[e] += __shfl_down(p[e], off);
  }
  if (lane == 0) {
    int i0 = 0; float v0 = p[0];
    #pragma unroll
    for (int e = 1; e < NE; e++) if (p[e] > v0) { v0 = p[e]; i0 = e; }
    int i1 = -1; float v1 = -3.0e38f;
    #pragma unroll
    for (int e = 0; e < NE; e++) if (e != i0 && p[e] > v1) { v1 = p[e]; i1 = e; }
    float ev = __expf(v1 - v0);
    float w0 = 1.0f / (1.0f + ev);
    float w1 = ev / (1.0f + ev);
    wts[t * 2 + 0] = w0;
    wts[t * 2 + 1] = w1;
    int pos0 = atomicAdd(&counts[i0], 1);
    lists[i0 * T + pos0] = t;               // k-slot 0
    int pos1 = atomicAdd(&counts[i1], 1);
    lists[i1 * T + pos1] = (1 << 16) | t;   // k-slot 1
  }
}

// ---------------------------------------------------------------- MoE FFN part 1: h = silu(x@w1)*(x@w3)
__global__ __launch_bounds__(256) void moe_ffn1_kernel(const float* __restrict__ xn,
    const float* __restrict__ w1, const float* __restrict__ w3,
    const int* __restrict__ counts, const int* __restrict__ lists, float* __restrict__ hbuf) {
  int e = blockIdx.z;
  int ne = counts[e];
  int row0 = blockIdx.y * 64;
  if (row0 >= ne) return;
  int col0 = blockIdx.x * 64;
  __shared__ float AsT[16][68];
  __shared__ float B1s[16][68];
  __shared__ float B2s[16][68];
  __shared__ int toks[64];
  int tid = threadIdx.x;
  if (tid < 64) toks[tid] = (row0 + tid < ne) ? lists[e * T + row0 + tid] : -1;
  __syncthreads();
  const float* W1 = w1 + (size_t)e * D * HID;
  const float* W3 = w3 + (size_t)e * D * HID;
  int tx = tid & 15, ty = tid >> 4;
  int ar = tid >> 2, akq = (tid & 3) * 4;
  int bk = tid >> 4, bcq = (tid & 15) * 4;
  int apk = toks[ar];
  const float* arow = (apk >= 0) ? &xn[(apk & 0xFFFF) * D] : nullptr;
  float ag[4][4] = {}, au[4][4] = {};
  for (int k0 = 0; k0 < D; k0 += 16) {
    float4 a4 = arow ? *(const float4*)&arow[k0 + akq] : float4{0.f, 0.f, 0.f, 0.f};
    float4 b14 = *(const float4*)&W1[(size_t)(k0 + bk) * HID + col0 + bcq];
    float4 b34 = *(const float4*)&W3[(size_t)(k0 + bk) * HID + col0 + bcq];
    AsT[akq + 0][ar] = a4.x; AsT[akq + 1][ar] = a4.y;
    AsT[akq + 2][ar] = a4.z; AsT[akq + 3][ar] = a4.w;
    *(float4*)&B1s[bk][bcq] = b14;
    *(float4*)&B2s[bk][bcq] = b34;
    __syncthreads();
    #pragma unroll
    for (int kk = 0; kk < 16; kk++) {
      float4 av = *(const float4*)&AsT[kk][ty * 4];
      float4 b1v = *(const float4*)&B1s[kk][tx * 4];
      float4 b2v = *(const float4*)&B2s[kk][tx * 4];
      float a[4] = {av.x, av.y, av.z, av.w};
      float b1[4] = {b1v.x, b1v.y, b1v.z, b1v.w};
      float b2[4] = {b2v.x, b2v.y, b2v.z, b2v.w};
      #pragma unroll
      for (int i = 0; i < 4; i++)
        #pragma unroll
        for (int j = 0; j < 4; j++) { ag[i][j] += a[i] * b1[j]; au[i][j] += a[i] * b2[j]; }
    }
    __syncthreads();
  }
  #pragma unroll
  for (int i = 0; i < 4; i++) {
    int r = ty * 4 + i;
    int pk = toks[r];
    if (pk < 0) continue;
    int t = pk & 0xFFFF, ks = pk >> 16;
    float* hp = hbuf + ((size_t)ks * T + t) * HID + col0;
    #pragma unroll
    for (int j = 0; j < 4; j++) {
      float g = ag[i][j], u = au[i][j];
      float sg = g / (1.0f + __expf(-g));
      hp[tx * 4 + j] = sg * u;
    }
  }
}

// ---------------------------------------------------------------- MoE FFN part 2: y[ks][t] = h@w2
__global__ __launch_bounds__(256) void moe_ffn2_kernel(const float* __restrict__ hbuf,
    const float* __restrict__ w2, const int* __restrict__ counts, const int* __restrict__ lists,
    float* __restrict__ ybuf) {
  int e = blockIdx.z;
  int ne = counts[e];
  int row0 = blockIdx.y * 64;
  if (row0 >= ne) return;
  int col0 = blockIdx.x * 64;
  __shared__ float AsT[16][68];
  __shared__ float Bs[16][68];
  __shared__ int toks[64];
  int tid = threadIdx.x;
  if (tid < 64) toks[tid] = (row0 + tid < ne) ? lists[e * T + row0 + tid] : -1;
  __syncthreads();
  const float* W2 = w2 + (size_t)e * HID * D;
  int tx = tid & 15, ty = tid >> 4;
  int ar = tid >> 2, akq = (tid & 3) * 4;
  int bk = tid >> 4, bcq = (tid & 15) * 4;
  int apk = toks[ar];
  const float* arow = (apk >= 0) ? &hbuf[((size_t)(apk >> 16) * T + (apk & 0xFFFF)) * HID] : nullptr;
  float acc[4][4] = {};
  for (int k0 = 0; k0 < HID; k0 += 16) {
    float4 a4 = arow ? *(const float4*)&arow[k0 + akq] : float4{0.f, 0.f, 0.f, 0.f};
    float4 b4 = *(const float4*)&W2[(size_t)(k0 + bk) * D + col0 + bcq];
    AsT[akq + 0][ar] = a4.x; AsT[akq + 1][ar] = a4.y;
    AsT[akq + 2][ar] = a4.z; AsT[akq + 3][ar] = a4.w;
    *(float4*)&Bs[bk][bcq] = b4;
    __syncthreads();
    #pragma unroll
    for (int kk = 0; kk < 16; kk++) {
      float4 av = *(const float4*)&AsT[kk][ty * 4];
      float4 bv = *(const float4*)&Bs[kk][tx * 4];
      float a[4] = {av.x, av.y, av.z, av.w};
      float b[4] = {bv.x, bv.y, bv.z, bv.w};
      #pragma unroll
      for (int i = 0; i < 4; i++)
        #pragma unroll
        for (int j = 0; j < 4; j++) acc[i][j] += a[i] * b[j];
    }
    __syncthreads();
  }
  #pragma unroll
  for (int i = 0; i < 4; i++) {
    int r = ty * 4 + i;
    int pk = toks[r];
    if (pk < 0) continue;
    int t = pk & 0xFFFF, ks = pk >> 16;
    float* yp = ybuf + ((size_t)ks * T + t) * D + col0;
    #pragma unroll
    for (int j = 0; j < 4; j++) yp[tx * 4 + j] = acc[i][j];
  }
}

// ---------------------------------------------------------------- combine: x += w0*y0 + w1*y1
__global__ __launch_bounds__(256) void moe_combine_kernel(const float* __restrict__ ybuf,
    const float* __restrict__ wts, float* __restrict__ x) {
  int idx = blockIdx.x * 256 + threadIdx.x;  // T*D
  int t = idx >> 9;
  x[idx] += wts[t * 2] * ybuf[idx] + wts[t * 2 + 1] * ybuf[(size_t)T * D + idx];
}

// ---------------------------------------------------------------- final logits GEMM (B transposed)
// 128x128 tile, 8x8 per thread
__global__ __launch_bounds__(256) void logits_kernel(const float* __restrict__ xf,
    const float* __restrict__ emb, float* __restrict__ out) {
  int v0 = blockIdx.x * 128;
  int r0 = blockIdx.y * 128;
  __shared__ float AsT[16][132];
  __shared__ float Bs[16][132];
  int tid = threadIdx.x;
  int tx = tid & 15, ty = tid >> 4;
  float acc[8][8] = {};
  for (int k0 = 0; k0 < D; k0 += 16) {
    #pragma unroll
    for (int i = 0; i < 2; i++) {
      int el = tid + i * 256;          // 512 float4s: 128 rows x 4 kquads
      int r = el >> 2, kq = (el & 3) * 4;
      float4 a4 = *(const float4*)&xf[(r0 + r) * D + k0 + kq];
      float4 b4 = *(const float4*)&emb[(size_t)(v0 + r) * D + k0 + kq];
      AsT[kq + 0][r] = a4.x; AsT[kq + 1][r] = a4.y;
      AsT[kq + 2][r] = a4.z; AsT[kq + 3][r] = a4.w;
      Bs[kq + 0][r] = b4.x; Bs[kq + 1][r] = b4.y;
      Bs[kq + 2][r] = b4.z; Bs[kq + 3][r] = b4.w;
    }
    __syncthreads();
    #pragma unroll
    for (int kk = 0; kk < 16; kk++) {
      float4 av0 = *(const float4*)&AsT[kk][ty * 8];
      float4 av1 = *(const float4*)&AsT[kk][ty * 8 + 4];
      float4 bv0 = *(const float4*)&Bs[kk][tx * 8];
      float4 bv1 = *(const float4*)&Bs[kk][tx * 8 + 4];
      float a[8] = {av0.x, av0.y, av0.z, av0.w, av1.x, av1.y, av1.z, av1.w};
      float b[8] = {bv0.x, bv0.y, bv0.z, bv0.w, bv1.x, bv1.y, bv1.z, bv1.w};
      #pragma unroll
      for (int i = 0; i < 8; i++)
        #pragma unroll
        for (int j = 0; j < 8; j++) acc[i][j] += a[i] * b[j];
    }
    __syncthreads();
  }
  #pragma unroll
  for (int i = 0; i < 8; i++) {
    size_t rowoff = (size_t)(r0 + ty * 8 + i) * V + v0;
    #pragma unroll
    for (int j = 0; j < 8; j++) out[rowoff + tx * 8 + j] = acc[i][j];
  }
}

// ---------------------------------------------------------------- launch
extern "C" void kernel_launch(void* const* d_in, const int* in_sizes, int n_in,
                              void* d_out, int out_size, void* d_ws, size_t ws_size,
                              hipStream_t stream) {
  const int*   ids     = (const int*)d_in[0];
  const float* emb     = (const float*)d_in[1];
  const float* attn_nw = (const float*)d_in[2];
  const float* wq      = (const float*)d_in[3];
  const float* wk      = (const float*)d_in[4];
  const float* wv      = (const float*)d_in[5];
  const float* wo      = (const float*)d_in[6];
  const float* moe_nw  = (const float*)d_in[7];
  const float* rww     = (const float*)d_in[8];
  const float* w1      = (const float*)d_in[9];
  const float* w2      = (const float*)d_in[10];
  const float* w3      = (const float*)d_in[11];
  const float* fnw     = (const float*)d_in[12];
  float* out = (float*)d_out;

  char* p = (char*)d_ws;
  auto alloc = [&](size_t bytes) -> void* {
    void* r = (void*)p;
    p += (bytes + 255) & ~(size_t)255;
    return r;
  };
  float* x    = (float*)alloc((size_t)T * D * 4);
  float* xn   = (float*)alloc((size_t)T * D * 4);
  float* q    = (float*)alloc((size_t)T * D * 4);
  float* k    = (float*)alloc((size_t)T * D * 4);
  float* v    = (float*)alloc((size_t)T * D * 4);
  float* attn = (float*)alloc((size_t)T * D * 4);
  float* cost = (float*)alloc((size_t)T * 32 * 4);
  float* sint = (float*)alloc((size_t)T * 32 * 4);
  float* wts  = (float*)alloc((size_t)T * 2 * 4);
  int*   counts = (int*)alloc(NE * 4);
  int*   lists  = (int*)alloc((size_t)NE * T * 4);
  float* hbuf = (float*)alloc((size_t)2 * T * HID * 4);
  float* ybuf = (float*)alloc((size_t)2 * T * D * 4);

  embed_kernel<<<T * D / 256, 256, 0, stream>>>(ids, emb, x);
  rope_cache_kernel<<<T * 32 / 256, 256, 0, stream>>>(cost, sint);

  for (int l = 0; l < NL; l++) {
    rmsnorm_kernel<<<T, 256, 0, stream>>>(x, attn_nw + (size_t)l * D, xn);
    gemm_qkv_kernel<<<dim3(24, 32), 256, 0, stream>>>(xn,
        wq + (size_t)l * D * D, wk + (size_t)l * D * D, wv + (size_t)l * D * D, q, k, v);
    rope_apply_kernel<<<H * T * 32 / 256, 256, 0, stream>>>(q, k, cost, sint);
    attn_kernel<<<dim3(T, H), 256, 0, stream>>>(q, k, v, attn);
    gemm_wo_kernel<<<dim3(8, 32), 256, 0, stream>>>(attn, wo + (size_t)l * D * D, x);
    rmsnorm_kernel<<<T, 256, 0, stream>>>(x, moe_nw + (size_t)l * D, xn);
    hipMemsetAsync(counts, 0, NE * sizeof(int), stream);
    router_kernel<<<T / 4, 256, 0, stream>>>(xn, rww + (size_t)l * D * NE, wts, counts, lists);
    moe_ffn1_kernel<<<dim3(HID / 64, T / 64, NE), 256, 0, stream>>>(xn,
        w1 + (size_t)l * NE * D * HID, w3 + (size_t)l * NE * D * HID, counts, lists, hbuf);
    moe_ffn2_kernel<<<dim3(D / 64, T / 64, NE), 256, 0, stream>>>(hbuf,
        w2 + (size_t)l * NE * HID * D, counts, lists, ybuf);
    moe_combine_kernel<<<T * D / 256, 256, 0, stream>>>(ybuf, wts, x);
  }

  rmsnorm_kernel<<<T, 256, 0, stream>>>(x, fnw, xn);
  logits_kernel<<<dim3(V / 128, T / 128), 256, 0, stream>>>(xn, emb, out);
}

// Round 3
// 5585.362 us; speedup vs baseline: 1.7582x; 1.7582x over previous
//
#include <hip/hip_runtime.h>
#include <math.h>

#define V 32000
#define D 512
#define H 8
#define NL 4
#define HID 2048
#define NE 8
#define T 2048
#define HD 64
#define QBLK 64
#define KVBLK 64

// ---------------------------------------------------------------- embedding
__global__ __launch_bounds__(256) void embed_kernel(const int* __restrict__ ids,
                                                    const float* __restrict__ emb,
                                                    float* __restrict__ x) {
  int idx = blockIdx.x * 256 + threadIdx.x;   // T*D total
  int t = idx >> 9;
  x[idx] = emb[(size_t)ids[t] * D + (idx & 511)];
}

// ---------------------------------------------------------------- rope cache (f64 once)
__global__ __launch_bounds__(256) void rope_cache_kernel(float* __restrict__ cost,
                                                         float* __restrict__ sint) {
  int idx = blockIdx.x * 256 + threadIdx.x;   // T*32 total
  int t = idx >> 5, j = idx & 31;
  double inv = pow(10000.0, -(double)j / 32.0);
  double ang = (double)t * inv;
  cost[idx] = (float)cos(ang);
  sint[idx] = (float)sin(ang);
}

// ---------------------------------------------------------------- rmsnorm (block per token)
__global__ __launch_bounds__(256) void rmsnorm_kernel(const float* __restrict__ in,
                                                      const float* __restrict__ w,
                                                      float* __restrict__ out) {
  int t = blockIdx.x;
  int tid = threadIdx.x;
  float a = in[t * D + tid];
  float b = in[t * D + tid + 256];
  float ss = a * a + b * b;
  #pragma unroll
  for (int off = 32; off; off >>= 1) ss += __shfl_down(ss, off);
  __shared__ float red[4];
  if ((tid & 63) == 0) red[tid >> 6] = ss;
  __syncthreads();
  float tot = red[0] + red[1] + red[2] + red[3];
  float inv = rsqrtf(tot * (1.0f / D) + 1e-6f);
  out[t * D + tid]       = a * inv * w[tid];
  out[t * D + tid + 256] = b * inv * w[tid + 256];
}

// ---------------------------------------------------------------- fused QKV GEMM (N=1536)
__global__ __launch_bounds__(256) void gemm_qkv_kernel(const float* __restrict__ A,
    const float* __restrict__ wq, const float* __restrict__ wk, const float* __restrict__ wv,
    float* __restrict__ q, float* __restrict__ k, float* __restrict__ v) {
  __shared__ float AsT[16][68];
  __shared__ float Bs[16][68];
  int tid = threadIdx.x;
  int cg = blockIdx.x * 64;            // 0..1535
  int row0 = blockIdx.y * 64;
  int m = cg >> 9;                     // 0=q 1=k 2=v
  const float* W = (m == 0) ? wq : (m == 1) ? wk : wv;
  float* O = (m == 0) ? q : (m == 1) ? k : v;
  int col0 = cg & 511;
  int tx = tid & 15, ty = tid >> 4;
  int ar = tid >> 2, akq = (tid & 3) * 4;      // A staging coords
  int bk = tid >> 4, bcq = (tid & 15) * 4;     // B staging coords
  float acc[4][4] = {};
  for (int k0 = 0; k0 < D; k0 += 16) {
    float4 a4 = *(const float4*)&A[(row0 + ar) * D + k0 + akq];
    float4 b4 = *(const float4*)&W[(k0 + bk) * D + col0 + bcq];
    __syncthreads();
    AsT[akq + 0][ar] = a4.x; AsT[akq + 1][ar] = a4.y;
    AsT[akq + 2][ar] = a4.z; AsT[akq + 3][ar] = a4.w;
    *(float4*)&Bs[bk][bcq] = b4;
    __syncthreads();
    #pragma unroll
    for (int kk = 0; kk < 16; kk++) {
      float4 av = *(const float4*)&AsT[kk][ty * 4];
      float4 bv = *(const float4*)&Bs[kk][tx * 4];
      float a[4] = {av.x, av.y, av.z, av.w};
      float b[4] = {bv.x, bv.y, bv.z, bv.w};
      #pragma unroll
      for (int i = 0; i < 4; i++)
        #pragma unroll
        for (int j = 0; j < 4; j++) acc[i][j] += a[i] * b[j];
    }
  }
  #pragma unroll
  for (int i = 0; i < 4; i++) {
    int t = row0 + ty * 4 + i;
    #pragma unroll
    for (int j = 0; j < 4; j++) {
      int c = col0 + tx * 4 + j;
      int h = c >> 6, d = c & 63;
      O[((size_t)h * T + t) * HD + d] = acc[i][j];
    }
  }
}

// ---------------------------------------------------------------- WO GEMM + residual
__global__ __launch_bounds__(256) void gemm_wo_kernel(const float* __restrict__ A,
    const float* __restrict__ W, float* __restrict__ x) {
  __shared__ float AsT[16][68];
  __shared__ float Bs[16][68];
  int tid = threadIdx.x;
  int col0 = blockIdx.x * 64;
  int row0 = blockIdx.y * 64;
  int tx = tid & 15, ty = tid >> 4;
  int ar = tid >> 2, akq = (tid & 3) * 4;
  int bk = tid >> 4, bcq = (tid & 15) * 4;
  float acc[4][4] = {};
  for (int k0 = 0; k0 < D; k0 += 16) {
    float4 a4 = *(const float4*)&A[(row0 + ar) * D + k0 + akq];
    float4 b4 = *(const float4*)&W[(k0 + bk) * D + col0 + bcq];
    __syncthreads();
    AsT[akq + 0][ar] = a4.x; AsT[akq + 1][ar] = a4.y;
    AsT[akq + 2][ar] = a4.z; AsT[akq + 3][ar] = a4.w;
    *(float4*)&Bs[bk][bcq] = b4;
    __syncthreads();
    #pragma unroll
    for (int kk = 0; kk < 16; kk++) {
      float4 av = *(const float4*)&AsT[kk][ty * 4];
      float4 bv = *(const float4*)&Bs[kk][tx * 4];
      float a[4] = {av.x, av.y, av.z, av.w};
      float b[4] = {bv.x, bv.y, bv.z, bv.w};
      #pragma unroll
      for (int i = 0; i < 4; i++)
        #pragma unroll
        for (int j = 0; j < 4; j++) acc[i][j] += a[i] * b[j];
    }
  }
  #pragma unroll
  for (int i = 0; i < 4; i++) {
    int t = row0 + ty * 4 + i;
    #pragma unroll
    for (int j = 0; j < 4; j++) {
      int c = col0 + tx * 4 + j;
      x[t * D + c] = x[t * D + c] + acc[i][j];
    }
  }
}

// ---------------------------------------------------------------- rope apply (q and k)
__global__ __launch_bounds__(256) void rope_apply_kernel(float* __restrict__ q, float* __restrict__ k,
    const float* __restrict__ cost, const float* __restrict__ sint) {
  int idx = blockIdx.x * 256 + threadIdx.x;  // H*T*32
  int h = idx >> 16;
  int rem = idx & 65535;                     // t*32 + j
  int t = rem >> 5, j = rem & 31;
  float c = cost[rem], s = sint[rem];
  size_t base = ((size_t)h * T + t) * HD;
  float x1 = q[base + j], x2 = q[base + j + 32];
  q[base + j]      = x1 * c - x2 * s;
  q[base + j + 32] = x2 * c + x1 * s;
  x1 = k[base + j]; x2 = k[base + j + 32];
  k[base + j]      = x1 * c - x2 * s;
  k[base + j + 32] = x2 * c + x1 * s;
}

// ---------------------------------------------------------------- flash attention
// grid (T/64, H), 256 threads. 64x64 tiles, 4x4 per thread, online softmax.
__global__ __launch_bounds__(256) void attn_flash_kernel(const float* __restrict__ q,
    const float* __restrict__ k, const float* __restrict__ v, float* __restrict__ o) {
  int qb = blockIdx.x, h = blockIdx.y;
  int q0 = qb * QBLK;
  __shared__ float QsT[HD][68];     // Q^T [d][row]
  __shared__ float KPs[HD][68];     // K^T [d][col]; later P^T [j][row]
  __shared__ float Vs[KVBLK][68];   // V [j][d]
  int tid = threadIdx.x;
  int tx = tid & 15, ty = tid >> 4;
  int ar = tid >> 2;                 // row/col 0..63
  int aq0 = (tid & 3) * 4;           // d quad base
  const float* qh = q + (size_t)h * T * HD;
  const float* kh = k + (size_t)h * T * HD;
  const float* vh = v + (size_t)h * T * HD;

  // load Q tile transposed (4 float4 per thread)
  #pragma unroll
  for (int qq = 0; qq < 4; qq++) {
    int d0 = aq0 + qq * 16;
    float4 a4 = *(const float4*)&qh[(size_t)(q0 + ar) * HD + d0];
    QsT[d0 + 0][ar] = a4.x; QsT[d0 + 1][ar] = a4.y;
    QsT[d0 + 2][ar] = a4.z; QsT[d0 + 3][ar] = a4.w;
  }

  float m_i[4] = {-3e38f, -3e38f, -3e38f, -3e38f};
  float l_i[4] = {};
  float acc[4][4] = {};
  int nkv = qb + 1;
  for (int kb = 0; kb < nkv; kb++) {
    // prefetch K,V tiles into registers
    float4 kreg[4], vreg[4];
    #pragma unroll
    for (int qq = 0; qq < 4; qq++) {
      int d0 = aq0 + qq * 16;
      kreg[qq] = *(const float4*)&kh[(size_t)(kb * KVBLK + ar) * HD + d0];
      vreg[qq] = *(const float4*)&vh[(size_t)(kb * KVBLK + ar) * HD + d0];
    }
    __syncthreads();   // previous PV reads done (also covers Q staging on first iter)
    #pragma unroll
    for (int qq = 0; qq < 4; qq++) {
      int d0 = aq0 + qq * 16;
      KPs[d0 + 0][ar] = kreg[qq].x; KPs[d0 + 1][ar] = kreg[qq].y;
      KPs[d0 + 2][ar] = kreg[qq].z; KPs[d0 + 3][ar] = kreg[qq].w;
      *(float4*)&Vs[ar][d0] = vreg[qq];
    }
    __syncthreads();
    // S = Q.K^T (4x4 per thread)
    float s[4][4] = {};
    #pragma unroll 8
    for (int d = 0; d < HD; d++) {
      float4 av = *(const float4*)&QsT[d][ty * 4];
      float4 bv = *(const float4*)&KPs[d][tx * 4];
      float a[4] = {av.x, av.y, av.z, av.w};
      float b[4] = {bv.x, bv.y, bv.z, bv.w};
      #pragma unroll
      for (int i = 0; i < 4; i++)
        #pragma unroll
        for (int j = 0; j < 4; j++) s[i][j] += a[i] * b[j];
    }
    bool diag = (kb == qb);
    #pragma unroll
    for (int i = 0; i < 4; i++)
      #pragma unroll
      for (int j = 0; j < 4; j++) {
        s[i][j] *= 0.125f;
        if (diag && (tx * 4 + j > ty * 4 + i)) s[i][j] = -3e38f;
      }
    // online softmax update (row stats across tx lanes)
    #pragma unroll
    for (int i = 0; i < 4; i++) {
      float rm = fmaxf(fmaxf(s[i][0], s[i][1]), fmaxf(s[i][2], s[i][3]));
      #pragma unroll
      for (int off = 1; off < 16; off <<= 1) rm = fmaxf(rm, __shfl_xor(rm, off));
      float mnew = fmaxf(m_i[i], rm);
      float corr = __expf(m_i[i] - mnew);
      m_i[i] = mnew;
      l_i[i] *= corr;
      #pragma unroll
      for (int j = 0; j < 4; j++) acc[i][j] *= corr;
      float psum = 0.0f;
      #pragma unroll
      for (int j = 0; j < 4; j++) { s[i][j] = __expf(s[i][j] - mnew); psum += s[i][j]; }
      #pragma unroll
      for (int off = 1; off < 16; off <<= 1) psum += __shfl_xor(psum, off);
      l_i[i] += psum;
    }
    __syncthreads();   // all QK reads of KPs done
    // write P^T into KPs: [j][row]
    #pragma unroll
    for (int i = 0; i < 4; i++)
      #pragma unroll
      for (int j = 0; j < 4; j++) KPs[tx * 4 + j][ty * 4 + i] = s[i][j];
    __syncthreads();
    // acc += P.V
    #pragma unroll 8
    for (int j = 0; j < KVBLK; j++) {
      float4 pv_ = *(const float4*)&KPs[j][ty * 4];
      float4 vv = *(const float4*)&Vs[j][tx * 4];
      float a[4] = {pv_.x, pv_.y, pv_.z, pv_.w};
      float b[4] = {vv.x, vv.y, vv.z, vv.w};
      #pragma unroll
      for (int i = 0; i < 4; i++)
        #pragma unroll
        for (int jj = 0; jj < 4; jj++) acc[i][jj] += a[i] * b[jj];
    }
  }
  // epilogue
  #pragma unroll
  for (int i = 0; i < 4; i++) {
    float inv = 1.0f / l_i[i];
    int t = q0 + ty * 4 + i;
    #pragma unroll
    for (int j = 0; j < 4; j++)
      o[(size_t)t * D + h * HD + tx * 4 + j] = acc[i][j] * inv;
  }
}

// ---------------------------------------------------------------- router: logits, top2, lists
__global__ __launch_bounds__(256) void router_kernel(const float* __restrict__ xn,
    const float* __restrict__ rw, float* __restrict__ wts,
    int* __restrict__ counts, int* __restrict__ lists) {
  int tid = threadIdx.x;
  int wv_ = tid >> 6, lane = tid & 63;
  int t = blockIdx.x * 4 + wv_;
  float p[NE] = {};
  #pragma unroll
  for (int i = 0; i < D / 64; i++) {
    int d = lane + i * 64;
    float xd = xn[t * D + d];
    #pragma unroll
    for (int e = 0; e < NE; e++) p[e] += xd * rw[d * NE + e];
  }
  #pragma unroll
  for (int e = 0; e < NE; e++) {
    #pragma unroll
    for (int off = 32; off; off >>= 1) p[e] += __shfl_down(p[e], off);
  }
  if (lane == 0) {
    int i0 = 0; float v0 = p[0];
    #pragma unroll
    for (int e = 1; e < NE; e++) if (p[e] > v0) { v0 = p[e]; i0 = e; }
    int i1 = -1; float v1 = -3.0e38f;
    #pragma unroll
    for (int e = 0; e < NE; e++) if (e != i0 && p[e] > v1) { v1 = p[e]; i1 = e; }
    float ev = __expf(v1 - v0);
    float w0 = 1.0f / (1.0f + ev);
    float w1 = ev / (1.0f + ev);
    wts[t * 2 + 0] = w0;
    wts[t * 2 + 1] = w1;
    int pos0 = atomicAdd(&counts[i0], 1);
    lists[i0 * T + pos0] = t;               // k-slot 0
    int pos1 = atomicAdd(&counts[i1], 1);
    lists[i1 * T + pos1] = (1 << 16) | t;   // k-slot 1
  }
}

// ---------------------------------------------------------------- MoE FFN part 1 (128x128, 8x8/thread)
__global__ __launch_bounds__(256, 1) void moe_ffn1_kernel(const float* __restrict__ xn,
    const float* __restrict__ w1, const float* __restrict__ w3,
    const int* __restrict__ counts, const int* __restrict__ lists, float* __restrict__ hbuf) {
  int e = blockIdx.z;
  int ne = counts[e];
  int row0 = blockIdx.y * 128;
  if (row0 >= ne) return;
  int col0 = blockIdx.x * 128;
  __shared__ float AsT[16][132];
  __shared__ float B1s[16][132];
  __shared__ float B2s[16][132];
  __shared__ int toks[128];
  int tid = threadIdx.x;
  if (tid < 128) toks[tid] = (row0 + tid < ne) ? lists[e * T + row0 + tid] : -1;
  __syncthreads();
  const float* W1 = w1 + (size_t)e * D * HID;
  const float* W3 = w3 + (size_t)e * D * HID;
  int tx = tid & 15, ty = tid >> 4;
  int r0a = tid >> 2, kqa = (tid & 3) * 4;     // A: rows r0a, r0a+64
  int kkb = tid >> 5, cqb = (tid & 31) * 4;    // B: k rows kkb, kkb+8
  int pk0 = toks[r0a], pk1 = toks[r0a + 64];
  const float* arow0 = (pk0 >= 0) ? &xn[(pk0 & 0xFFFF) * D] : nullptr;
  const float* arow1 = (pk1 >= 0) ? &xn[(pk1 & 0xFFFF) * D] : nullptr;
  float ag[8][8] = {}, au[8][8] = {};
  for (int k0 = 0; k0 < D; k0 += 16) {
    float4 a40 = arow0 ? *(const float4*)&arow0[k0 + kqa] : float4{0.f,0.f,0.f,0.f};
    float4 a41 = arow1 ? *(const float4*)&arow1[k0 + kqa] : float4{0.f,0.f,0.f,0.f};
    float4 b10 = *(const float4*)&W1[(size_t)(k0 + kkb) * HID + col0 + cqb];
    float4 b11 = *(const float4*)&W1[(size_t)(k0 + kkb + 8) * HID + col0 + cqb];
    float4 b30 = *(const float4*)&W3[(size_t)(k0 + kkb) * HID + col0 + cqb];
    float4 b31 = *(const float4*)&W3[(size_t)(k0 + kkb + 8) * HID + col0 + cqb];
    __syncthreads();
    AsT[kqa + 0][r0a] = a40.x; AsT[kqa + 1][r0a] = a40.y;
    AsT[kqa + 2][r0a] = a40.z; AsT[kqa + 3][r0a] = a40.w;
    AsT[kqa + 0][r0a + 64] = a41.x; AsT[kqa + 1][r0a + 64] = a41.y;
    AsT[kqa + 2][r0a + 64] = a41.z; AsT[kqa + 3][r0a + 64] = a41.w;
    *(float4*)&B1s[kkb][cqb] = b10;
    *(float4*)&B1s[kkb + 8][cqb] = b11;
    *(float4*)&B2s[kkb][cqb] = b30;
    *(float4*)&B2s[kkb + 8][cqb] = b31;
    __syncthreads();
    #pragma unroll
    for (int kk = 0; kk < 16; kk++) {
      float4 av0 = *(const float4*)&AsT[kk][ty * 8];
      float4 av1 = *(const float4*)&AsT[kk][ty * 8 + 4];
      float4 b1v0 = *(const float4*)&B1s[kk][tx * 8];
      float4 b1v1 = *(const float4*)&B1s[kk][tx * 8 + 4];
      float4 b2v0 = *(const float4*)&B2s[kk][tx * 8];
      float4 b2v1 = *(const float4*)&B2s[kk][tx * 8 + 4];
      float a[8]  = {av0.x, av0.y, av0.z, av0.w, av1.x, av1.y, av1.z, av1.w};
      float b1[8] = {b1v0.x, b1v0.y, b1v0.z, b1v0.w, b1v1.x, b1v1.y, b1v1.z, b1v1.w};
      float b2[8] = {b2v0.x, b2v0.y, b2v0.z, b2v0.w, b2v1.x, b2v1.y, b2v1.z, b2v1.w};
      #pragma unroll
      for (int i = 0; i < 8; i++)
        #pragma unroll
        for (int j = 0; j < 8; j++) { ag[i][j] += a[i] * b1[j]; au[i][j] += a[i] * b2[j]; }
    }
  }
  #pragma unroll
  for (int i = 0; i < 8; i++) {
    int rr = ty * 8 + i;
    int pk = toks[rr];
    if (pk < 0) continue;
    int t = pk & 0xFFFF, ks = pk >> 16;
    float* hp = hbuf + ((size_t)ks * T + t) * HID + col0;
    #pragma unroll
    for (int j = 0; j < 8; j++) {
      float g = ag[i][j], u = au[i][j];
      float sg = g / (1.0f + __expf(-g));
      hp[tx * 8 + j] = sg * u;
    }
  }
}

// ---------------------------------------------------------------- MoE FFN part 2 (128x128, 8x8/thread)
__global__ __launch_bounds__(256, 1) void moe_ffn2_kernel(const float* __restrict__ hbuf,
    const float* __restrict__ w2, const int* __restrict__ counts, const int* __restrict__ lists,
    float* __restrict__ ybuf) {
  int e = blockIdx.z;
  int ne = counts[e];
  int row0 = blockIdx.y * 128;
  if (row0 >= ne) return;
  int col0 = blockIdx.x * 128;
  __shared__ float AsT[16][132];
  __shared__ float Bs[16][132];
  __shared__ int toks[128];
  int tid = threadIdx.x;
  if (tid < 128) toks[tid] = (row0 + tid < ne) ? lists[e * T + row0 + tid] : -1;
  __syncthreads();
  const float* W2 = w2 + (size_t)e * HID * D;
  int tx = tid & 15, ty = tid >> 4;
  int r0a = tid >> 2, kqa = (tid & 3) * 4;
  int kkb = tid >> 5, cqb = (tid & 31) * 4;
  int pk0 = toks[r0a], pk1 = toks[r0a + 64];
  const float* arow0 = (pk0 >= 0) ? &hbuf[((size_t)(pk0 >> 16) * T + (pk0 & 0xFFFF)) * HID] : nullptr;
  const float* arow1 = (pk1 >= 0) ? &hbuf[((size_t)(pk1 >> 16) * T + (pk1 & 0xFFFF)) * HID] : nullptr;
  float acc[8][8] = {};
  for (int k0 = 0; k0 < HID; k0 += 16) {
    float4 a40 = arow0 ? *(const float4*)&arow0[k0 + kqa] : float4{0.f,0.f,0.f,0.f};
    float4 a41 = arow1 ? *(const float4*)&arow1[k0 + kqa] : float4{0.f,0.f,0.f,0.f};
    float4 b0 = *(const float4*)&W2[(size_t)(k0 + kkb) * D + col0 + cqb];
    float4 b1 = *(const float4*)&W2[(size_t)(k0 + kkb + 8) * D + col0 + cqb];
    __syncthreads();
    AsT[kqa + 0][r0a] = a40.x; AsT[kqa + 1][r0a] = a40.y;
    AsT[kqa + 2][r0a] = a40.z; AsT[kqa + 3][r0a] = a40.w;
    AsT[kqa + 0][r0a + 64] = a41.x; AsT[kqa + 1][r0a + 64] = a41.y;
    AsT[kqa + 2][r0a + 64] = a41.z; AsT[kqa + 3][r0a + 64] = a41.w;
    *(float4*)&Bs[kkb][cqb] = b0;
    *(float4*)&Bs[kkb + 8][cqb] = b1;
    __syncthreads();
    #pragma unroll
    for (int kk = 0; kk < 16; kk++) {
      float4 av0 = *(const float4*)&AsT[kk][ty * 8];
      float4 av1 = *(const float4*)&AsT[kk][ty * 8 + 4];
      float4 bv0 = *(const float4*)&Bs[kk][tx * 8];
      float4 bv1 = *(const float4*)&Bs[kk][tx * 8 + 4];
      float a[8] = {av0.x, av0.y, av0.z, av0.w, av1.x, av1.y, av1.z, av1.w};
      float b[8] = {bv0.x, bv0.y, bv0.z, bv0.w, bv1.x, bv1.y, bv1.z, bv1.w};
      #pragma unroll
      for (int i = 0; i < 8; i++)
        #pragma unroll
        for (int j = 0; j < 8; j++) acc[i][j] += a[i] * b[j];
    }
  }
  #pragma unroll
  for (int i = 0; i < 8; i++) {
    int rr = ty * 8 + i;
    int pk = toks[rr];
    if (pk < 0) continue;
    int t = pk & 0xFFFF, ks = pk >> 16;
    float* yp = ybuf + ((size_t)ks * T + t) * D + col0;
    #pragma unroll
    for (int j = 0; j < 8; j++) yp[tx * 8 + j] = acc[i][j];
  }
}

// ---------------------------------------------------------------- combine: x += w0*y0 + w1*y1
__global__ __launch_bounds__(256) void moe_combine_kernel(const float* __restrict__ ybuf,
    const float* __restrict__ wts, float* __restrict__ x) {
  int idx = blockIdx.x * 256 + threadIdx.x;  // T*D
  int t = idx >> 9;
  x[idx] += wts[t * 2] * ybuf[idx] + wts[t * 2 + 1] * ybuf[(size_t)T * D + idx];
}

// ---------------------------------------------------------------- final logits GEMM (B transposed)
__global__ __launch_bounds__(256) void logits_kernel(const float* __restrict__ xf,
    const float* __restrict__ emb, float* __restrict__ out) {
  int v0 = blockIdx.x * 128;
  int r0 = blockIdx.y * 128;
  __shared__ float AsT[16][132];
  __shared__ float Bs[16][132];
  int tid = threadIdx.x;
  int tx = tid & 15, ty = tid >> 4;
  float acc[8][8] = {};
  for (int k0 = 0; k0 < D; k0 += 16) {
    float4 pa[2], pb[2];
    #pragma unroll
    for (int i = 0; i < 2; i++) {
      int el = tid + i * 256;          // 512 float4s: 128 rows x 4 kquads
      int r = el >> 2, kq = (el & 3) * 4;
      pa[i] = *(const float4*)&xf[(r0 + r) * D + k0 + kq];
      pb[i] = *(const float4*)&emb[(size_t)(v0 + r) * D + k0 + kq];
    }
    __syncthreads();
    #pragma unroll
    for (int i = 0; i < 2; i++) {
      int el = tid + i * 256;
      int r = el >> 2, kq = (el & 3) * 4;
      AsT[kq + 0][r] = pa[i].x; AsT[kq + 1][r] = pa[i].y;
      AsT[kq + 2][r] = pa[i].z; AsT[kq + 3][r] = pa[i].w;
      Bs[kq + 0][r] = pb[i].x; Bs[kq + 1][r] = pb[i].y;
      Bs[kq + 2][r] = pb[i].z; Bs[kq + 3][r] = pb[i].w;
    }
    __syncthreads();
    #pragma unroll
    for (int kk = 0; kk < 16; kk++) {
      float4 av0 = *(const float4*)&AsT[kk][ty * 8];
      float4 av1 = *(const float4*)&AsT[kk][ty * 8 + 4];
      float4 bv0 = *(const float4*)&Bs[kk][tx * 8];
      float4 bv1 = *(const float4*)&Bs[kk][tx * 8 + 4];
      float a[8] = {av0.x, av0.y, av0.z, av0.w, av1.x, av1.y, av1.z, av1.w};
      float b[8] = {bv0.x, bv0.y, bv0.z, bv0.w, bv1.x, bv1.y, bv1.z, bv1.w};
      #pragma unroll
      for (int i = 0; i < 8; i++)
        #pragma unroll
        for (int j = 0; j < 8; j++) acc[i][j] += a[i] * b[j];
    }
  }
  #pragma unroll
  for (int i = 0; i < 8; i++) {
    size_t rowoff = (size_t)(r0 + ty * 8 + i) * V + v0;
    #pragma unroll
    for (int j = 0; j < 8; j++) out[rowoff + tx * 8 + j] = acc[i][j];
  }
}

// ---------------------------------------------------------------- launch
extern "C" void kernel_launch(void* const* d_in, const int* in_sizes, int n_in,
                              void* d_out, int out_size, void* d_ws, size_t ws_size,
                              hipStream_t stream) {
  const int*   ids     = (const int*)d_in[0];
  const float* emb     = (const float*)d_in[1];
  const float* attn_nw = (const float*)d_in[2];
  const float* wq      = (const float*)d_in[3];
  const float* wk      = (const float*)d_in[4];
  const float* wv      = (const float*)d_in[5];
  const float* wo      = (const float*)d_in[6];
  const float* moe_nw  = (const float*)d_in[7];
  const float* rww     = (const float*)d_in[8];
  const float* w1      = (const float*)d_in[9];
  const float* w2      = (const float*)d_in[10];
  const float* w3      = (const float*)d_in[11];
  const float* fnw     = (const float*)d_in[12];
  float* out = (float*)d_out;

  char* p = (char*)d_ws;
  auto alloc = [&](size_t bytes) -> void* {
    void* r = (void*)p;
    p += (bytes + 255) & ~(size_t)255;
    return r;
  };
  float* x    = (float*)alloc((size_t)T * D * 4);
  float* xn   = (float*)alloc((size_t)T * D * 4);
  float* q    = (float*)alloc((size_t)T * D * 4);
  float* k    = (float*)alloc((size_t)T * D * 4);
  float* v    = (float*)alloc((size_t)T * D * 4);
  float* attn = (float*)alloc((size_t)T * D * 4);
  float* cost = (float*)alloc((size_t)T * 32 * 4);
  float* sint = (float*)alloc((size_t)T * 32 * 4);
  float* wts  = (float*)alloc((size_t)T * 2 * 4);
  int*   counts = (int*)alloc(NE * 4);
  int*   lists  = (int*)alloc((size_t)NE * T * 4);
  float* hbuf = (float*)alloc((size_t)2 * T * HID * 4);
  float* ybuf = (float*)alloc((size_t)2 * T * D * 4);

  embed_kernel<<<T * D / 256, 256, 0, stream>>>(ids, emb, x);
  rope_cache_kernel<<<T * 32 / 256, 256, 0, stream>>>(cost, sint);

  for (int l = 0; l < NL; l++) {
    rmsnorm_kernel<<<T, 256, 0, stream>>>(x, attn_nw + (size_t)l * D, xn);
    gemm_qkv_kernel<<<dim3(24, 32), 256, 0, stream>>>(xn,
        wq + (size_t)l * D * D, wk + (size_t)l * D * D, wv + (size_t)l * D * D, q, k, v);
    rope_apply_kernel<<<H * T * 32 / 256, 256, 0, stream>>>(q, k, cost, sint);
    attn_flash_kernel<<<dim3(T / QBLK, H), 256, 0, stream>>>(q, k, v, attn);
    gemm_wo_kernel<<<dim3(8, 32), 256, 0, stream>>>(attn, wo + (size_t)l * D * D, x);
    rmsnorm_kernel<<<T, 256, 0, stream>>>(x, moe_nw + (size_t)l * D, xn);
    hipMemsetAsync(counts, 0, NE * sizeof(int), stream);
    router_kernel<<<T / 4, 256, 0, stream>>>(xn, rww + (size_t)l * D * NE, wts, counts, lists);
    moe_ffn1_kernel<<<dim3(HID / 128, T / 128, NE), 256, 0, stream>>>(xn,
        w1 + (size_t)l * NE * D * HID, w3 + (size_t)l * NE * D * HID, counts, lists, hbuf);
    moe_ffn2_kernel<<<dim3(D / 128, T / 128, NE), 256, 0, stream>>>(hbuf,
        w2 + (size_t)l * NE * HID * D, counts, lists, ybuf);
    moe_combine_kernel<<<T * D / 256, 256, 0, stream>>>(ybuf, wts, x);
  }

  rmsnorm_kernel<<<T, 256, 0, stream>>>(x, fnw, xn);
  logits_kernel<<<dim3(V / 128, T / 128), 256, 0, stream>>>(xn, emb, out);
}